// Round 10
// baseline (28.964 us; speedup 1.0000x reference)
//
#include <hip/hip_runtime.h>
#include <math.h>

#define HH 256
#define WW 256
#define CC 32
#define NN 4
#define NBLK (NN * CC * 4)        // 512 blocks: plane*4 + q, 64 rows each
#define POISON 0xAAAAAAAAu
// ws layout (uint words): [0..512) partial flags (bid-indexed, data-as-flag);
// counter for batch n at word 512 + n*256 (1 KB apart -> 4 distinct lines).
#define CNT_BASE 512
#define CNT_STRIDE 256

typedef float floatx4 __attribute__((ext_vector_type(4)));

// Single fused dispatch, 512 blocks x 256 threads (all co-resident: 2/CU).
// Phase 1: pool own 64 rows -> relaxed agent store of raw sum (flag IS data),
//          then relaxed agent fetch_add on this batch's counter.
// Sync:    ONE poller per block on the batch counter, s_sleep(32) backoff
//          (~150M polls/line/s total -- 16x below the rate that saturated
//          the TCC in round 7). Then 128 threads one-shot read the batch's
//          flags, re-polling only if poison (first call / reorder window;
//          steady-state replays hit instantly since values are identical).
// Phase 2: filter taps + 3x3 stencil on the same 64 rows (L2-warm) + affine,
//          nontemporal stores.
__global__ __launch_bounds__(256) void fused_dynfilt(
    const float* __restrict__ x,
    const float* __restrict__ conv_w,
    const float* __restrict__ bn_gamma, const float* __restrict__ bn_beta,
    const float* __restrict__ bn_mean, const float* __restrict__ bn_var,
    const float* __restrict__ lamb_l, const float* __restrict__ lamb_h,
    const float* __restrict__ inside_all,
    unsigned int* __restrict__ ws,
    float* __restrict__ out)
{
    const int bid   = blockIdx.x;        // plane*4 + q
    const int plane = bid >> 2;
    const int q     = bid & 3;
    const int n = plane >> 5;
    const int c = plane & 31;
    const int g = c >> 2;
    const int t = threadIdx.x;
    const int lane = t & 63;
    const int w = t >> 6;

    const float* xp = x + (size_t)plane * HH * WW;

    // ---------------- phase 1: pool rows [q*64, q*64+64) ----------------------
    {
        const float4* xb = (const float4*)(xp + (size_t)q * 64 * WW);
        float s = 0.f;
        #pragma unroll
        for (int k = 0; k < 16; ++k) {   // 4096 float4 / 256 threads
            const float4 v = xb[k * 256 + t];
            s += (v.x + v.y) + (v.z + v.w);
        }
        #pragma unroll
        for (int off = 32; off > 0; off >>= 1) s += __shfl_down(s, off, 64);
        __shared__ float wsum[4];
        if (lane == 0) wsum[w] = s;
        __syncthreads();
        if (t == 0) {
            const float tot = (wsum[0] + wsum[1]) + (wsum[2] + wsum[3]);
            __hip_atomic_store(ws + bid, __float_as_uint(tot),
                               __ATOMIC_RELAXED, __HIP_MEMORY_SCOPE_AGENT);
            __hip_atomic_fetch_add(ws + CNT_BASE + n * CNT_STRIDE, 1u,
                                   __ATOMIC_RELAXED, __HIP_MEMORY_SCOPE_AGENT);
        }
    }

    // ---------------- sync: one poller per block ------------------------------
    __shared__ float sraw[128];
    __shared__ float spooled[CC];
    __shared__ float sfilt[9];
    __shared__ float scoef[3];

    if (t == 0) {
        const unsigned int tgt = POISON + 128u;   // 128 blocks per batch
        const unsigned int* cnt = ws + CNT_BASE + n * CNT_STRIDE;
        while (__hip_atomic_load(cnt, __ATOMIC_RELAXED,
                                 __HIP_MEMORY_SCOPE_AGENT) != tgt)
            __builtin_amdgcn_s_sleep(32);
    }
    __syncthreads();

    if (t < 128) {   // one-shot flag read; rare re-poll on poison
        const unsigned int* pp = ws + n * 128 + t;
        unsigned int bits = __hip_atomic_load(pp, __ATOMIC_RELAXED,
                                              __HIP_MEMORY_SCOPE_AGENT);
        while (bits == POISON) {
            __builtin_amdgcn_s_sleep(2);
            bits = __hip_atomic_load(pp, __ATOMIC_RELAXED,
                                     __HIP_MEMORY_SCOPE_AGENT);
        }
        sraw[t] = __uint_as_float(bits);   // sraw[c*4 + q]
    }
    __syncthreads();

    if (t < CC) {
        const float* sr = sraw + t * 4;
        spooled[t] = ((sr[0] + sr[1]) + (sr[2] + sr[3])) * (1.0f / (HH * WW));
    }
    __syncthreads();

    // ---------------- filter taps + affine coefs ------------------------------
    if (t < 9) {
        const int j = g * 9 + t;
        const float4* wrow = (const float4*)(conv_w + (size_t)j * CC);
        float f = 0.f;
        #pragma unroll
        for (int k = 0; k < 8; ++k) {
            const float4 wv = wrow[k];
            f += spooled[4*k]   * wv.x + spooled[4*k+1] * wv.y
               + spooled[4*k+2] * wv.z + spooled[4*k+3] * wv.w;
        }
        f = (f - bn_mean[j]) * bn_gamma[j] * rsqrtf(bn_var[j] + 1e-5f) + bn_beta[j];
        sfilt[t] = tanhf(f);
    } else if (t == 9) {
        const float ia = inside_all[c];
        const float ll = lamb_l[c];
        scoef[0] = (ia + 1.0f) * ll;              // cA
        scoef[1] = -ia * spooled[c] * ll;         // cB
        scoef[2] = lamb_h[c] + 1.0f;              // cC
    }
    __syncthreads();

    const float f0 = sfilt[0], f1 = sfilt[1], f2 = sfilt[2];
    const float f3 = sfilt[3], f4 = sfilt[4], f5 = sfilt[5];
    const float f6 = sfilt[6], f7 = sfilt[7], f8 = sfilt[8];
    const float cA = scoef[0], cB = scoef[1], cC = scoef[2];

    // ---------------- phase 2: stencil on the same 64 rows (L2-warm) ----------
    #pragma unroll
    for (int e2 = 0; e2 < 2; ++e2) {
        const int row0 = q * 64 + e2 * 32 + w * 8;

        float4 v[10];
        #pragma unroll
        for (int i = 0; i < 10; ++i) {
            int gr = row0 - 1 + i;
            gr = (gr < 0) ? -gr : ((gr >= HH) ? (2 * HH - 2 - gr) : gr);
            v[i] = *(const float4*)(xp + (size_t)gr * WW + lane * 4);
        }

        float lf[10], rf[10];
        #pragma unroll
        for (int i = 0; i < 10; ++i) {
            lf[i] = __shfl_up(v[i].w, 1, 64);
            if (lane == 0) lf[i] = v[i].y;       // col -1 -> col 1
            rf[i] = __shfl_down(v[i].x, 1, 64);
            if (lane == 63) rf[i] = v[i].z;      // col 256 -> col 254
        }

        float* op = out + (size_t)plane * HH * WW + (size_t)row0 * WW + lane * 4;

        #pragma unroll
        for (int rr = 0; rr < 8; ++rr) {
            const float4 a = v[rr], b = v[rr + 1], cv = v[rr + 2];
            const float al = lf[rr], bl = lf[rr + 1], cl = lf[rr + 2];
            const float ar = rf[rr], br = rf[rr + 1], cr = rf[rr + 2];

            const float s0 = f0*al  + f1*a.x + f2*a.y + f3*bl  + f4*b.x + f5*b.y + f6*cl   + f7*cv.x + f8*cv.y;
            const float s1 = f0*a.x + f1*a.y + f2*a.z + f3*b.x + f4*b.y + f5*b.z + f6*cv.x + f7*cv.y + f8*cv.z;
            const float s2 = f0*a.y + f1*a.z + f2*a.w + f3*b.y + f4*b.z + f5*b.w + f6*cv.y + f7*cv.z + f8*cv.w;
            const float s3 = f0*a.z + f1*a.w + f2*ar  + f3*b.z + f4*b.w + f5*br  + f6*cv.z + f7*cv.w + f8*cr;

            floatx4 o;
            o.x = cA * s0 + cB + cC * b.x;
            o.y = cA * s1 + cB + cC * b.y;
            o.z = cA * s2 + cB + cC * b.z;
            o.w = cA * s3 + cB + cC * b.w;
            __builtin_nontemporal_store(o, (floatx4*)(op + (size_t)rr * WW));
        }
    }
}

extern "C" void kernel_launch(void* const* d_in, const int* in_sizes, int n_in,
                              void* d_out, int out_size, void* d_ws, size_t ws_size,
                              hipStream_t stream) {
    const float* x          = (const float*)d_in[0];
    const float* conv_w     = (const float*)d_in[1];
    const float* bn_gamma   = (const float*)d_in[2];
    const float* bn_beta    = (const float*)d_in[3];
    const float* bn_mean    = (const float*)d_in[4];
    const float* bn_var     = (const float*)d_in[5];
    const float* lamb_l     = (const float*)d_in[6];
    const float* lamb_h     = (const float*)d_in[7];
    const float* inside_all = (const float*)d_in[8];
    float* out       = (float*)d_out;
    unsigned int* ws = (unsigned int*)d_ws;

    // Re-poison ONLY the 4 batch counters (words 512,768,1024,1280). Flags are
    // data-as-flag and rewritten with identical values every call.
    hipMemsetAsync((char*)d_ws + CNT_BASE * sizeof(unsigned int), 0xAA,
                   (3 * CNT_STRIDE + 1) * sizeof(unsigned int), stream);

    hipLaunchKernelGGL(fused_dynfilt, dim3(NBLK), dim3(256), 0, stream,
                       x, conv_w, bn_gamma, bn_beta, bn_mean, bn_var,
                       lamb_l, lamb_h, inside_all, ws, out);
}

// Round 11
// 22.413 us; speedup vs baseline: 1.2923x; 1.2923x over previous
//
#include <hip/hip_runtime.h>
#include <math.h>

#define HH 256
#define WW 256
#define CC 32
#define NN 4

typedef float floatx4 __attribute__((ext_vector_type(4)));

// ---------------- Kernel A: partial pool, one block per (plane, 16-row chunk) ----
__global__ __launch_bounds__(256) void pool_partial(const float* __restrict__ x,
                                                    float* __restrict__ partials) {
    const int bid   = blockIdx.x;        // plane*16 + e
    const int plane = bid >> 4;
    const int e     = bid & 15;
    const float4* xb = (const float4*)(x + (size_t)plane * HH * WW + (size_t)e * 16 * WW);
    const int t = threadIdx.x;
    float4 a0 = xb[t];
    float4 a1 = xb[t + 256];
    float4 a2 = xb[t + 512];
    float4 a3 = xb[t + 768];
    float s = ((a0.x + a0.y) + (a0.z + a0.w)) + ((a1.x + a1.y) + (a1.z + a1.w))
            + ((a2.x + a2.y) + (a2.z + a2.w)) + ((a3.x + a3.y) + (a3.z + a3.w));
    #pragma unroll
    for (int off = 32; off > 0; off >>= 1) s += __shfl_down(s, off, 64);
    __shared__ float wsum[4];
    if ((t & 63) == 0) wsum[t >> 6] = s;
    __syncthreads();
    if (t == 0) partials[bid] = (wsum[0] + wsum[1]) + (wsum[2] + wsum[3]);
}

// ---------------- Kernel B: filter taps + stencil + affine -----------------------
// Grid: plane*8 + e (1024 blocks). Block: 4 waves x 8-row strips of a 32-row chunk.
__global__ __launch_bounds__(256) void dynfilt(
    const float* __restrict__ x,
    const float* __restrict__ conv_w,
    const float* __restrict__ bn_gamma, const float* __restrict__ bn_beta,
    const float* __restrict__ bn_mean, const float* __restrict__ bn_var,
    const float* __restrict__ lamb_l, const float* __restrict__ lamb_h,
    const float* __restrict__ inside_all,
    const float* __restrict__ partials,
    float* __restrict__ out)
{
    __shared__ float spooled[CC];
    __shared__ float sfilt[9];
    __shared__ float scoef[3];

    const int bid   = blockIdx.x;
    const int plane = bid >> 3;
    const int e     = bid & 7;
    const int n = plane >> 5;
    const int c = plane & 31;
    const int g = c >> 2;
    const int t = threadIdx.x;
    const int lane = t & 63;
    const int w = t >> 6;

    const float* xp = x + (size_t)plane * HH * WW;
    const int row0 = e * 32 + w * 8;

    // ---- issue ALL long-latency loads up front --------------------------------
    float4 v[10];
    #pragma unroll
    for (int i = 0; i < 10; ++i) {
        int gr = row0 - 1 + i;
        gr = (gr < 0) ? -gr : ((gr >= HH) ? (2 * HH - 2 - gr) : gr);
        v[i] = *(const float4*)(xp + (size_t)gr * WW + lane * 4);
    }

    float psum = 0.f;
    if (t < CC) {
        const float* pp = partials + ((size_t)n * CC + t) * 16;
        #pragma unroll
        for (int k = 0; k < 16; ++k) psum += pp[k];
    }

    float4 wreg[8];
    if (t < 9) {
        const float4* wrow = (const float4*)(conv_w + (size_t)(g * 9 + t) * CC);
        #pragma unroll
        for (int k = 0; k < 8; ++k) wreg[k] = wrow[k];
    }

    // ---- tiny scalar phase ----------------------------------------------------
    if (t < CC) spooled[t] = psum * (1.0f / (HH * WW));
    __syncthreads();

    if (t < 9) {
        const int j = g * 9 + t;
        float f = 0.f;
        #pragma unroll
        for (int k = 0; k < 8; ++k) {
            f += spooled[4*k]   * wreg[k].x + spooled[4*k+1] * wreg[k].y
               + spooled[4*k+2] * wreg[k].z + spooled[4*k+3] * wreg[k].w;
        }
        f = (f - bn_mean[j]) * bn_gamma[j] * rsqrtf(bn_var[j] + 1e-5f) + bn_beta[j];
        sfilt[t] = tanhf(f);
    } else if (t == 9) {
        const float ia = inside_all[c];
        const float ll = lamb_l[c];
        scoef[0] = (ia + 1.0f) * ll;              // cA
        scoef[1] = -ia * spooled[c] * ll;         // cB
        scoef[2] = lamb_h[c] + 1.0f;              // cC
    }
    __syncthreads();

    const float f0 = sfilt[0], f1 = sfilt[1], f2 = sfilt[2];
    const float f3 = sfilt[3], f4 = sfilt[4], f5 = sfilt[5];
    const float f6 = sfilt[6], f7 = sfilt[7], f8 = sfilt[8];
    const float cA = scoef[0], cB = scoef[1], cC = scoef[2];

    // ---- halo columns via cross-lane; col -1 -> 1, col 256 -> 254 -------------
    float lf[10], rf[10];
    #pragma unroll
    for (int i = 0; i < 10; ++i) {
        lf[i] = __shfl_up(v[i].w, 1, 64);
        if (lane == 0) lf[i] = v[i].y;
        rf[i] = __shfl_down(v[i].x, 1, 64);
        if (lane == 63) rf[i] = v[i].z;
    }

    float* op = out + (size_t)plane * HH * WW + (size_t)row0 * WW + lane * 4;

    #pragma unroll
    for (int rr = 0; rr < 8; ++rr) {
        const float4 a = v[rr], b = v[rr + 1], cv = v[rr + 2];
        const float al = lf[rr], bl = lf[rr + 1], cl = lf[rr + 2];
        const float ar = rf[rr], br = rf[rr + 1], cr = rf[rr + 2];

        const float s0 = f0*al  + f1*a.x + f2*a.y + f3*bl  + f4*b.x + f5*b.y + f6*cl   + f7*cv.x + f8*cv.y;
        const float s1 = f0*a.x + f1*a.y + f2*a.z + f3*b.x + f4*b.y + f5*b.z + f6*cv.x + f7*cv.y + f8*cv.z;
        const float s2 = f0*a.y + f1*a.z + f2*a.w + f3*b.y + f4*b.z + f5*b.w + f6*cv.y + f7*cv.z + f8*cv.w;
        const float s3 = f0*a.z + f1*a.w + f2*ar  + f3*b.z + f4*b.w + f5*br  + f6*cv.z + f7*cv.w + f8*cr;

        floatx4 o;
        o.x = cA * s0 + cB + cC * b.x;
        o.y = cA * s1 + cB + cC * b.y;
        o.z = cA * s2 + cB + cC * b.z;
        o.w = cA * s3 + cB + cC * b.w;
        // streaming store: no L2/L3 write-allocate, keep x resident in cache
        __builtin_nontemporal_store(o, (floatx4*)(op + (size_t)rr * WW));
    }
}

extern "C" void kernel_launch(void* const* d_in, const int* in_sizes, int n_in,
                              void* d_out, int out_size, void* d_ws, size_t ws_size,
                              hipStream_t stream) {
    const float* x          = (const float*)d_in[0];
    const float* conv_w     = (const float*)d_in[1];
    const float* bn_gamma   = (const float*)d_in[2];
    const float* bn_beta    = (const float*)d_in[3];
    const float* bn_mean    = (const float*)d_in[4];
    const float* bn_var     = (const float*)d_in[5];
    const float* lamb_l     = (const float*)d_in[6];
    const float* lamb_h     = (const float*)d_in[7];
    const float* inside_all = (const float*)d_in[8];
    float* out      = (float*)d_out;
    float* partials = (float*)d_ws;   // NN*CC*16 = 2048 floats

    hipLaunchKernelGGL(pool_partial, dim3(NN * CC * 16), dim3(256), 0, stream, x, partials);
    hipLaunchKernelGGL(dynfilt, dim3(NN * CC * 8), dim3(256), 0, stream,
                       x, conv_w, bn_gamma, bn_beta, bn_mean, bn_var,
                       lamb_l, lamb_h, inside_all, partials, out);
}